// Round 2
// baseline (208.729 us; speedup 1.0000x reference)
//
#include <hip/hip_runtime.h>
#include <hip/hip_fp16.h>
#include <cmath>

#define N_NODES 50000
#define DIM 64
#define E_EDGES 800000
#define FIX32 65536.0f       // 2^16 fixed-point scale for deg (24-bit field, max 256)
#define NB_A 98              // score/sort blocks: 98 * 512 = 50176 >= 50000
#define NB_EDGE 384          // edge-pass blocks (measured sweet spot; 768 was slower, r13)
#define NRUNS 98             // sorted runs of 64 entering phase B
#define NXCD 8               // MI355X: 8 XCDs, per-XCD L2 (non-coherent)
#define BUCKET8 24           // per-(xcd,node) bucket capacity; deg<=45 total, Bin(45,1/8)
                             // per-XCD; P(overflow) ~1e-6 even at 2x scheduler skew
#define XW_BLOCKS 782        // ceil(50000 / 64)

// XCD id of the executing wave (HW-verified on gfx950: s_getreg HW_REG_XCC_ID, m09)
__device__ __forceinline__ int xcc_id() {
    int x;
    asm volatile("s_getreg_b32 %0, hwreg(HW_REG_XCC_ID)" : "=s"(x));
    return x & 7;
}

// TCC(L2)-local atomic add with return. NO sc1 -> executes in the local XCD's L2
// (agent-scope HIP atomicAdd emits sc1 and round-trips the coherent fabric: that
// was the measured 64B*E WRITE floor, r10-r15). Only XCD-local atomicity is
// required because each XCD owns a private copy of the counter array.
__device__ __forceinline__ unsigned int atomic_add_l2(unsigned int* addr, unsigned int val) {
    unsigned int old;
    asm volatile("global_atomic_add %0, %1, %2, off sc0\n\t"
                 "s_waitcnt vmcnt(0)"
                 : "=&v"(old) : "v"(addr), "v"(val) : "memory");
    return old;
}

// ======== wave-register bitonic helpers (comparator: val desc, idx asc) ========
__device__ __forceinline__ void wave_sort64(float& v, int& idx, int lane) {
    #pragma unroll
    for (int k = 2; k <= 64; k <<= 1) {
        #pragma unroll
        for (int j = k >> 1; j > 0; j >>= 1) {
            float ov = __shfl_xor(v, j);
            int   oi = __shfl_xor(idx, j);
            bool lower = ((lane & j) == 0);
            bool up    = ((lane & k) == 0);
            bool mine_prec = (v > ov) || (v == ov && idx < oi);
            bool keep = up ? (lower == mine_prec) : (lower != mine_prec);
            if (!keep) { v = ov; idx = oi; }
        }
    }
}

// A (desc, in regs) merged with B (bv/bi must hold B[63-lane]); result: top-64 desc
__device__ __forceinline__ void wave_merge_top64(float& v, int& idx,
                                                 float bv, int bi, int lane) {
    bool a_prec = (v > bv) || (v == bv && idx < bi);
    if (!a_prec) { v = bv; idx = bi; }
    #pragma unroll
    for (int j = 32; j > 0; j >>= 1) {
        float ov = __shfl_xor(v, j);
        int   oi = __shfl_xor(idx, j);
        bool lower = ((lane & j) == 0);
        bool mine_prec = (v > ov) || (v == ov && idx < oi);
        bool keep = (lower == mine_prec);   // up = true (full-width merge)
        if (!keep) { v = ov; idx = oi; }
    }
}

// ------ fused: score + top-k phase A (blocks<98) + SINGLE edge pass (all blocks) ------
// Per-XCD private counters (packed8) + per-XCD bucket lists (ren8), L2-local atomics.
__global__ __launch_bounds__(512) void score_topk_edge_kernel(
    const float* __restrict__ x, const float* __restrict__ p,
    float* __restrict__ cand_val, int* __restrict__ cand_idx,
    const int* __restrict__ ei, const float* __restrict__ ew,
    unsigned int* __restrict__ packed8, unsigned int* __restrict__ ren8) {
    __shared__ float sv[512];
    __shared__ int   si[512];
    int t = threadIdx.x, lane = t & 63, wvid = t >> 6;
    if (blockIdx.x < NB_A) {
        int g = blockIdx.x * 512 + t;
        float v; int idx;
        if (g < N_NODES) {
            const float4* x4 = (const float4*)(x + (size_t)g * DIM);
            const float4* p4 = (const float4*)p;
            float dot = 0.f, pn = 0.f;
            #pragma unroll
            for (int k = 0; k < 16; k++) {
                float4 xv = x4[k], pv = p4[k];
                dot += xv.x * pv.x + xv.y * pv.y + xv.z * pv.z + xv.w * pv.w;
                pn  += pv.x * pv.x + pv.y * pv.y + pv.z * pv.z + pv.w * pv.w;
            }
            v = dot / sqrtf(pn);
            idx = g;
        } else { v = -INFINITY; idx = 0x7fffffff; }
        wave_sort64(v, idx, lane);
        sv[t] = v; si[t] = idx;
        __syncthreads();
        if (wvid == 0) {
            #pragma unroll
            for (int r = 1; r < 8; r++)
                wave_merge_top64(v, idx, sv[r * 64 + 63 - lane], si[r * 64 + 63 - lane], lane);
            cand_val[blockIdx.x * 64 + lane] = v;
            cand_idx[blockIdx.x * 64 + lane] = idx;
        }
    }
    // single edge pass: L2-local deg atomic + per-XCD bucket record
    int xcc = xcc_id();
    unsigned int* mypk = packed8 + (size_t)xcc * N_NODES;
    unsigned int* myren = ren8 + (size_t)xcc * N_NODES * BUCKET8;
    for (int e = blockIdx.x * 512 + t; e < E_EDGES; e += NB_EDGE * 512) {
        int r = ei[e], c = ei[E_EDGES + e];
        float wgt = ew[e];
        unsigned int q = (unsigned int)(wgt * FIX32);
        unsigned int old = atomic_add_l2(&mypk[c], (1u << 24) | q);
        unsigned int pos = old >> 24;
        if (pos < BUCKET8) {
            __half hw = __float2half(wgt);
            unsigned int rec = ((unsigned int)__half_as_ushort(hw) << 16) | (unsigned int)r;
            myren[(size_t)c * BUCKET8 + pos] = rec;
        }
    }
}

// ---------------- top-k phase B: merge 98 runs, build x_tilde (1 block) ----------------
__global__ __launch_bounds__(1024) void topk_b_kernel(
    const float* __restrict__ cand_val, const int* __restrict__ cand_idx,
    const float* __restrict__ x, float* __restrict__ x_tilde) {
    __shared__ float rsv[16 * 64];
    __shared__ int   rsi[16 * 64];
    __shared__ float tval[64];
    __shared__ int   perm[64];
    int t = threadIdx.x, lane = t & 63, wv = t >> 6;
    int r0 = wv * 8;
    float v; int idx;
    if (r0 < NRUNS) { v = cand_val[r0 * 64 + lane]; idx = cand_idx[r0 * 64 + lane]; }
    else            { v = -INFINITY; idx = 0x7fffffff; }
    for (int r = r0 + 1; r < r0 + 8 && r < NRUNS; r++)
        wave_merge_top64(v, idx, cand_val[r * 64 + 63 - lane],
                         cand_idx[r * 64 + 63 - lane], lane);
    rsv[wv * 64 + lane] = v; rsi[wv * 64 + lane] = idx;
    __syncthreads();
    if (wv == 0) {
        v = rsv[lane]; idx = rsi[lane];
        for (int r = 1; r < 16; r++)
            wave_merge_top64(v, idx, rsv[r * 64 + 63 - lane],
                             rsi[r * 64 + 63 - lane], lane);
        tval[lane] = tanhf(v);
        perm[lane] = idx;
    }
    __syncthreads();
    for (int i = t; i < 4096; i += 1024) {
        int j = i >> 6, kk = i & 63;
        x_tilde[i] = x[perm[j] * DIM + kk] * tval[j];
    }
}

// ---------------- GRU step (16 blocks x 256, 4 rows per block) ----------------
__global__ __launch_bounds__(256) void gru_kernel(
    const float* __restrict__ xt, const float* __restrict__ initW,
    const float* __restrict__ Wih, const float* __restrict__ Whh,
    const float* __restrict__ bih, const float* __restrict__ bhh,
    float* __restrict__ Wout) {
    __shared__ float xrow_s[256], hrow_s[256];
    int t = threadIdx.x;
    int i = blockIdx.x * 4 + (t >> 6);   // row 0..63
    int j = t & 63;
    int li = (t >> 6) * 64 + j;
    xrow_s[li] = xt[i * 64 + j];
    hrow_s[li] = initW[i * 64 + j];
    __syncthreads();
    int lb = (t >> 6) * 64;
    float gi_r = bih[j], gi_z = bih[j + 64], gi_n = bih[j + 128];
    float gh_r = bhh[j], gh_z = bhh[j + 64], gh_n = bhh[j + 128];
    for (int k = 0; k < 64; k++) {
        float xv = xrow_s[lb + k], hv = hrow_s[lb + k];
        gi_r += xv * Wih[j * 64 + k];
        gi_z += xv * Wih[(j + 64) * 64 + k];
        gi_n += xv * Wih[(j + 128) * 64 + k];
        gh_r += hv * Whh[j * 64 + k];
        gh_z += hv * Whh[(j + 64) * 64 + k];
        gh_n += hv * Whh[(j + 128) * 64 + k];
    }
    float r = 1.f / (1.f + expf(-(gi_r + gh_r)));
    float z = 1.f / (1.f + expf(-(gi_z + gh_z)));
    float nn = tanhf(gi_n + r * gh_n);
    Wout[i * 64 + j] = (1.f - z) * nn + z * hrow_s[lb + j];
}

// ---------------- xw = dinv[r] * (x @ W), output fp16 (pre-scaled rows) ----------------
__global__ __launch_bounds__(256) void xw_kernel(
    const float* __restrict__ x, const float* __restrict__ W,
    const unsigned int* __restrict__ packed8, __half* __restrict__ xwh) {
    __shared__ float Wl[64 * 64];
    __shared__ float Xl[64 * 64];
    __shared__ float dinv_s[64];
    int t = threadIdx.x;
    int r0 = blockIdx.x * 64;
    if (t < 64) {
        int r = r0 + t;
        unsigned int s = 0;
        if (r < N_NODES) {
            #pragma unroll
            for (int xx = 0; xx < NXCD; xx++)
                s += packed8[(size_t)xx * N_NODES + r] & 0xFFFFFFu;
        }
        dinv_s[t] = rsqrtf((float)s * (1.0f / FIX32) + 1.0f);
    }
    for (int i = t; i < 4096; i += 256) Wl[i] = W[i];
    for (int i = t; i < 4096; i += 256) {
        int r = r0 + (i >> 6);
        Xl[i] = (r < N_NODES) ? x[r0 * 64 + i] : 0.f;
    }
    __syncthreads();
    int j = t & 63, ty = t >> 6;
    float acc[16];
    #pragma unroll
    for (int rr = 0; rr < 16; rr++) acc[rr] = 0.f;
    for (int k = 0; k < 64; k++) {
        float wvv = Wl[k * 64 + j];
        #pragma unroll
        for (int rr = 0; rr < 16; rr++)
            acc[rr] += Xl[(ty * 16 + rr) * 64 + k] * wvv;
    }
    #pragma unroll
    for (int rr = 0; rr < 16; rr++) {
        int r = r0 + ty * 16 + rr;
        if (r < N_NODES)
            xwh[r * DIM + j] = __float2half(acc[rr] * dinv_s[ty * 16 + rr]);
    }
}

// ------- gather + fused head: wave per node, walks 8 per-XCD bucket lists -------
// agg[n] = dinv[n] * (xwh[n] + sum_e w_e * xwh[row_e]);  out = relu(agg) @ linW + b
__global__ __launch_bounds__(256) void gather_head_kernel(
    const unsigned int* __restrict__ packed8, const unsigned int* __restrict__ ren8,
    const float4* __restrict__ xwh,   // 8 float4 (= 64 halves) per row
    const float* __restrict__ linW, const float* __restrict__ linb,
    float* __restrict__ out) {
    int gid = blockIdx.x * blockDim.x + threadIdx.x;
    int n = gid >> 6, lane = gid & 63;
    if (n >= N_NODES) return;
    int c8 = lane & 7;        // columns c8*8 .. c8*8+7
    int slot = lane >> 3;     // 8 row-slots per wave
    // per-XCD counts -> lane's (list, slot) assignment + total weighted degree
    int xsel = -1, xslot = 0, pref = 0;
    unsigned int wfix = 0;
    #pragma unroll
    for (int xx = 0; xx < NXCD; xx++) {
        unsigned int pkx = packed8[(size_t)xx * N_NODES + n];   // broadcast load
        int cx = min((int)(pkx >> 24), BUCKET8);
        wfix += pkx & 0xFFFFFFu;
        if (lane >= pref && lane < pref + cx) { xsel = xx; xslot = lane - pref; }
        pref += cx;
    }
    int cnt = min(pref, 64);
    float di = rsqrtf((float)wfix * (1.0f / FIX32) + 1.0f);
    float acc[8];
    #pragma unroll
    for (int q = 0; q < 8; q++) acc[q] = 0.f;
    if (slot == 0) {
        float4 hv = xwh[n * 8 + c8];
        const __half2* h2 = reinterpret_cast<const __half2*>(&hv);
        #pragma unroll
        for (int q = 0; q < 4; q++) {
            float2 f = __half22float2(h2[q]);
            acc[2 * q]     = f.x;
            acc[2 * q + 1] = f.y;
        }
    }
    // fetch this lane's record (concatenated per-XCD lists, lane < cnt)
    int rv = 0; float wv = 0.f;
    if (xsel >= 0 && lane < cnt) {
        unsigned int rec = ren8[((size_t)xsel * N_NODES + n) * BUCKET8 + xslot];
        rv = (int)(rec & 0xFFFFu);
        __half_raw hr; hr.x = (unsigned short)(rec >> 16);
        wv = __half2float(__half(hr));
    }
    int G = (cnt + 7) >> 3;
    int g = 0;
    for (; g + 2 <= G; g += 2) {      // 16 independent gathers in flight
        int src0 = g * 8 + slot, src1 = src0 + 8;
        int   ra = __shfl(rv, src0);  float wa = __shfl(wv, src0);
        int   rb = __shfl(rv, src1);  float wb = __shfl(wv, src1);
        float4 ha = xwh[ra * 8 + c8];
        float4 hb = xwh[rb * 8 + c8];
        const __half2* h2a = reinterpret_cast<const __half2*>(&ha);
        const __half2* h2b = reinterpret_cast<const __half2*>(&hb);
        #pragma unroll
        for (int q = 0; q < 4; q++) {
            float2 fa = __half22float2(h2a[q]);
            float2 fb = __half22float2(h2b[q]);
            acc[2 * q]     += wa * fa.x + wb * fb.x;
            acc[2 * q + 1] += wa * fa.y + wb * fb.y;
        }
    }
    if (g < G) {
        int src = g * 8 + slot;
        int r = __shfl(rv, src);      // inactive slots: wv=0 -> no-op FMA
        float ww = __shfl(wv, src);
        float4 hv = xwh[r * 8 + c8];
        const __half2* h2 = reinterpret_cast<const __half2*>(&hv);
        #pragma unroll
        for (int q = 0; q < 4; q++) {
            float2 f = __half22float2(h2[q]);
            acc[2 * q]     += ww * f.x;
            acc[2 * q + 1] += ww * f.y;
        }
    }
    // reduce partial sums across the 8 slots (lane bits 3,4,5)
    #pragma unroll
    for (int q = 0; q < 8; q++) {
        acc[q] += __shfl_xor(acc[q], 8);
        acc[q] += __shfl_xor(acc[q], 16);
        acc[q] += __shfl_xor(acc[q], 32);
    }
    float pv = 0.f;
    #pragma unroll
    for (int q = 0; q < 8; q++)
        pv += fmaxf(di * acc[q], 0.f) * linW[c8 * 8 + q];
    pv += __shfl_xor(pv, 1); pv += __shfl_xor(pv, 2); pv += __shfl_xor(pv, 4);
    if (lane == 0) out[n] = pv + linb[0];
}

extern "C" void kernel_launch(void* const* d_in, const int* in_sizes, int n_in,
                              void* d_out, int out_size, void* d_ws, size_t ws_size,
                              hipStream_t stream) {
    const float* x     = (const float*)d_in[0];
    const int*   ei    = (const int*)d_in[1];
    const float* ew    = (const float*)d_in[2];
    const float* p     = (const float*)d_in[3];
    const float* initW = (const float*)d_in[4];
    const float* Wih   = (const float*)d_in[5];
    const float* Whh   = (const float*)d_in[6];
    const float* bih   = (const float*)d_in[7];
    const float* bhh   = (const float*)d_in[8];
    const float* linW  = (const float*)d_in[9];
    const float* linb  = (const float*)d_in[10];
    float* out = (float*)d_out;

    char* w = (char*)d_ws;
    unsigned int* packed8 = (unsigned int*)w; w += 4ull * NXCD * N_NODES;          // 1.6 MB
    unsigned int* ren8 = (unsigned int*)w;    w += 4ull * NXCD * N_NODES * BUCKET8; // 38.4 MB
    __half* xwh    = (__half*)w;   w += 2ull * (size_t)N_NODES * DIM;              // 6.4 MB
    float* cand_val= (float*)w;    w += 4ull * 8192;
    int*   cand_idx= (int*)w;      w += 4ull * 8192;
    float* x_tilde = (float*)w;    w += 4ull * 4096;
    float* W       = (float*)w;    w += 4ull * 4096;

    // zero the 8 per-XCD counter copies (capture-legal memset node)
    hipMemsetAsync(packed8, 0, 4ull * NXCD * N_NODES, stream);
    score_topk_edge_kernel<<<NB_EDGE, 512, 0, stream>>>(
        x, p, cand_val, cand_idx, ei, ew, packed8, ren8);
    topk_b_kernel<<<1, 1024, 0, stream>>>(cand_val, cand_idx, x, x_tilde);
    gru_kernel<<<16, 256, 0, stream>>>(x_tilde, initW, Wih, Whh, bih, bhh, W);
    xw_kernel<<<XW_BLOCKS, 256, 0, stream>>>(x, W, packed8, xwh);
    gather_head_kernel<<<(N_NODES * 64 + 255) / 256, 256, 0, stream>>>(
        packed8, ren8, (const float4*)xwh, linW, linb, out);
}

// Round 6
// 205.026 us; speedup vs baseline: 1.0181x; 1.0181x over previous
//
#include <hip/hip_runtime.h>
#include <hip/hip_fp16.h>
#include <cmath>

#define N_NODES 50000
#define NPAD 50016           // per-XCD packed stride; index N_NODES = dummy slot for OOB lanes
#define DIM 64
#define E_EDGES 800000
#define FIX32 65536.0f       // 2^16 fixed-point scale for deg (24-bit field, max 256)
#define NB_A 98              // score/sort blocks: 98 * 512 = 50176 >= 50000
#define NB_EDGE 391          // edge blocks: 391*512*4 = 800768 >= 800000 (4 edges/thread)
#define ESTRIDE (NB_EDGE * 512)
#define NRUNS 98             // sorted runs of 64 entering phase B
#define NXCD 8               // MI355X: 8 XCDs, per-XCD L2 (non-coherent)
#define BUCKET8 24           // per-(xcd,node) bucket capacity; deg ~Poisson(16) total,
                             // Poisson(2) per XCD; P(overflow) astronomically small
#define XW_BLOCKS 782        // ceil(50000 / 64)

// XCD id of the executing wave (HW-verified on gfx950: s_getreg HW_REG_XCC_ID, m09)
__device__ __forceinline__ int xcc_id() {
    int x;
    asm volatile("s_getreg_b32 %0, hwreg(HW_REG_XCC_ID)" : "=s"(x));
    return x & 7;
}

// ======== wave-register bitonic helpers (comparator: val desc, idx asc) ========
__device__ __forceinline__ void wave_sort64(float& v, int& idx, int lane) {
    #pragma unroll
    for (int k = 2; k <= 64; k <<= 1) {
        #pragma unroll
        for (int j = k >> 1; j > 0; j >>= 1) {
            float ov = __shfl_xor(v, j);
            int   oi = __shfl_xor(idx, j);
            bool lower = ((lane & j) == 0);
            bool up    = ((lane & k) == 0);
            bool mine_prec = (v > ov) || (v == ov && idx < oi);
            bool keep = up ? (lower == mine_prec) : (lower != mine_prec);
            if (!keep) { v = ov; idx = oi; }
        }
    }
}

// A (desc, in regs) merged with B (bv/bi must hold B[63-lane]); result: top-64 desc
__device__ __forceinline__ void wave_merge_top64(float& v, int& idx,
                                                 float bv, int bi, int lane) {
    bool a_prec = (v > bv) || (v == bv && idx < bi);
    if (!a_prec) { v = bv; idx = bi; }
    #pragma unroll
    for (int j = 32; j > 0; j >>= 1) {
        float ov = __shfl_xor(v, j);
        int   oi = __shfl_xor(idx, j);
        bool lower = ((lane & j) == 0);
        bool mine_prec = (v > ov) || (v == ov && idx < oi);
        bool keep = (lower == mine_prec);   // up = true (full-width merge)
        if (!keep) { v = ov; idx = oi; }
    }
}

// ------ fused: score + top-k phase A (blocks<98) + batched edge pass (all blocks) ------
// KEY CHANGE (r18; resubmitted r19-r21 — infra timeouts, still unmeasured): 4
// independent atomics issued back-to-back per thread, ONE vmcnt. Theory: edge pass
// was outstanding-limited (1 RMW in flight per wave = ~12/CU -> ~12G RMW/s at
// ~600cy latency, matching the measured 16G ops/s wall). 4x outstanding -> ~4x.
__global__ __launch_bounds__(512) void score_topk_edge_kernel(
    const float* __restrict__ x, const float* __restrict__ p,
    float* __restrict__ cand_val, int* __restrict__ cand_idx,
    const int* __restrict__ ei, const float* __restrict__ ew,
    unsigned int* __restrict__ packed8, unsigned int* __restrict__ ren8) {
    __shared__ float sv[512];
    __shared__ int   si[512];
    int t = threadIdx.x, lane = t & 63, wvid = t >> 6;
    if (blockIdx.x < NB_A) {
        int g = blockIdx.x * 512 + t;
        float v; int idx;
        if (g < N_NODES) {
            const float4* x4 = (const float4*)(x + (size_t)g * DIM);
            const float4* p4 = (const float4*)p;
            float dot = 0.f, pn = 0.f;
            #pragma unroll
            for (int k = 0; k < 16; k++) {
                float4 xv = x4[k], pv = p4[k];
                dot += xv.x * pv.x + xv.y * pv.y + xv.z * pv.z + xv.w * pv.w;
                pn  += pv.x * pv.x + pv.y * pv.y + pv.z * pv.z + pv.w * pv.w;
            }
            v = dot / sqrtf(pn);
            idx = g;
        } else { v = -INFINITY; idx = 0x7fffffff; }
        wave_sort64(v, idx, lane);
        sv[t] = v; si[t] = idx;
        __syncthreads();
        if (wvid == 0) {
            #pragma unroll
            for (int r = 1; r < 8; r++)
                wave_merge_top64(v, idx, sv[r * 64 + 63 - lane], si[r * 64 + 63 - lane], lane);
            cand_val[blockIdx.x * 64 + lane] = v;
            cand_idx[blockIdx.x * 64 + lane] = idx;
        }
    }
    // ---- batched edge pass: 4 edges/thread, 4 L2-local RMWs in flight ----
    int xcc = xcc_id();
    unsigned int* mypk  = packed8 + (size_t)xcc * NPAD;
    unsigned int* myren = ren8 + (size_t)xcc * N_NODES * BUCKET8;
    int e0 = blockIdx.x * 512 + t;       // 0 .. ESTRIDE-1
    int   rr[4]; int cc[4]; float wwv[4]; bool valid[4];
    #pragma unroll
    for (int k = 0; k < 4; k++) {
        int e = e0 + k * ESTRIDE;
        bool vld = (e < E_EDGES);
        int ie = vld ? e : 0;
        rr[k]  = ei[ie];
        cc[k]  = vld ? ei[E_EDGES + ie] : N_NODES;   // dummy slot for OOB
        wwv[k] = ew[ie];
        valid[k] = vld;
    }
    unsigned int q[4];
    unsigned int* ap[4];
    #pragma unroll
    for (int k = 0; k < 4; k++) {
        q[k] = valid[k] ? ((1u << 24) | (unsigned int)(wwv[k] * FIX32)) : 0u;
        ap[k] = &mypk[cc[k]];
    }
    unsigned int o0, o1, o2, o3;
    asm volatile(
        "global_atomic_add %0, %4, %8, off sc0\n\t"
        "global_atomic_add %1, %5, %9, off sc0\n\t"
        "global_atomic_add %2, %6, %10, off sc0\n\t"
        "global_atomic_add %3, %7, %11, off sc0\n\t"
        "s_waitcnt vmcnt(0)"
        : "=&v"(o0), "=&v"(o1), "=&v"(o2), "=&v"(o3)
        : "v"(ap[0]), "v"(ap[1]), "v"(ap[2]), "v"(ap[3]),
          "v"(q[0]), "v"(q[1]), "v"(q[2]), "v"(q[3])
        : "memory");
    unsigned int oo[4] = {o0, o1, o2, o3};
    #pragma unroll
    for (int k = 0; k < 4; k++) {
        unsigned int pos = oo[k] >> 24;
        if (valid[k] && pos < BUCKET8) {
            __half hw = __float2half(wwv[k]);
            unsigned int rec = ((unsigned int)__half_as_ushort(hw) << 16) | (unsigned int)rr[k];
            myren[(size_t)cc[k] * BUCKET8 + pos] = rec;
        }
    }
}

// ---------------- top-k phase B: merge 98 runs, build x_tilde (1 block) ----------------
__global__ __launch_bounds__(1024) void topk_b_kernel(
    const float* __restrict__ cand_val, const int* __restrict__ cand_idx,
    const float* __restrict__ x, float* __restrict__ x_tilde) {
    __shared__ float rsv[16 * 64];
    __shared__ int   rsi[16 * 64];
    __shared__ float tval[64];
    __shared__ int   perm[64];
    int t = threadIdx.x, lane = t & 63, wv = t >> 6;
    int r0 = wv * 8;
    float v; int idx;
    if (r0 < NRUNS) { v = cand_val[r0 * 64 + lane]; idx = cand_idx[r0 * 64 + lane]; }
    else            { v = -INFINITY; idx = 0x7fffffff; }
    for (int r = r0 + 1; r < r0 + 8 && r < NRUNS; r++)
        wave_merge_top64(v, idx, cand_val[r * 64 + 63 - lane],
                         cand_idx[r * 64 + 63 - lane], lane);
    rsv[wv * 64 + lane] = v; rsi[wv * 64 + lane] = idx;
    __syncthreads();
    if (wv == 0) {
        v = rsv[lane]; idx = rsi[lane];
        for (int r = 1; r < 16; r++)
            wave_merge_top64(v, idx, rsv[r * 64 + 63 - lane],
                             rsi[r * 64 + 63 - lane], lane);
        tval[lane] = tanhf(v);
        perm[lane] = idx;
    }
    __syncthreads();
    for (int i = t; i < 4096; i += 1024) {
        int j = i >> 6, kk = i & 63;
        x_tilde[i] = x[perm[j] * DIM + kk] * tval[j];
    }
}

// ---------------- GRU step (16 blocks x 256, 4 rows per block) ----------------
__global__ __launch_bounds__(256) void gru_kernel(
    const float* __restrict__ xt, const float* __restrict__ initW,
    const float* __restrict__ Wih, const float* __restrict__ Whh,
    const float* __restrict__ bih, const float* __restrict__ bhh,
    float* __restrict__ Wout) {
    __shared__ float xrow_s[256], hrow_s[256];
    int t = threadIdx.x;
    int i = blockIdx.x * 4 + (t >> 6);   // row 0..63
    int j = t & 63;
    int li = (t >> 6) * 64 + j;
    xrow_s[li] = xt[i * 64 + j];
    hrow_s[li] = initW[i * 64 + j];
    __syncthreads();
    int lb = (t >> 6) * 64;
    float gi_r = bih[j], gi_z = bih[j + 64], gi_n = bih[j + 128];
    float gh_r = bhh[j], gh_z = bhh[j + 64], gh_n = bhh[j + 128];
    for (int k = 0; k < 64; k++) {
        float xv = xrow_s[lb + k], hv = hrow_s[lb + k];
        gi_r += xv * Wih[j * 64 + k];
        gi_z += xv * Wih[(j + 64) * 64 + k];
        gi_n += xv * Wih[(j + 128) * 64 + k];
        gh_r += hv * Whh[j * 64 + k];
        gh_z += hv * Whh[(j + 64) * 64 + k];
        gh_n += hv * Whh[(j + 128) * 64 + k];
    }
    float r = 1.f / (1.f + expf(-(gi_r + gh_r)));
    float z = 1.f / (1.f + expf(-(gi_z + gh_z)));
    float nn = tanhf(gi_n + r * gh_n);
    Wout[i * 64 + j] = (1.f - z) * nn + z * hrow_s[lb + j];
}

// ---------------- xw = dinv[r] * (x @ W), output fp16 (pre-scaled rows) ----------------
__global__ __launch_bounds__(256) void xw_kernel(
    const float* __restrict__ x, const float* __restrict__ W,
    const unsigned int* __restrict__ packed8, __half* __restrict__ xwh) {
    __shared__ float Wl[64 * 64];
    __shared__ float Xl[64 * 64];
    __shared__ float dinv_s[64];
    int t = threadIdx.x;
    int r0 = blockIdx.x * 64;
    if (t < 64) {
        int r = r0 + t;
        unsigned int s = 0;
        if (r < N_NODES) {
            #pragma unroll
            for (int xx = 0; xx < NXCD; xx++)
                s += packed8[(size_t)xx * NPAD + r] & 0xFFFFFFu;
        }
        dinv_s[t] = rsqrtf((float)s * (1.0f / FIX32) + 1.0f);
    }
    for (int i = t; i < 4096; i += 256) Wl[i] = W[i];
    for (int i = t; i < 4096; i += 256) {
        int r = r0 + (i >> 6);
        Xl[i] = (r < N_NODES) ? x[r0 * 64 + i] : 0.f;
    }
    __syncthreads();
    int j = t & 63, ty = t >> 6;
    float acc[16];
    #pragma unroll
    for (int rr = 0; rr < 16; rr++) acc[rr] = 0.f;
    for (int k = 0; k < 64; k++) {
        float wvv = Wl[k * 64 + j];
        #pragma unroll
        for (int rr = 0; rr < 16; rr++)
            acc[rr] += Xl[(ty * 16 + rr) * 64 + k] * wvv;
    }
    #pragma unroll
    for (int rr = 0; rr < 16; rr++) {
        int r = r0 + ty * 16 + rr;
        if (r < N_NODES)
            xwh[r * DIM + j] = __float2half(acc[rr] * dinv_s[ty * 16 + rr]);
    }
}

// ------- gather + fused head: wave per node, walks 8 per-XCD bucket lists -------
// agg[n] = dinv[n] * (xwh[n] + sum_e w_e * xwh[row_e]);  out = relu(agg) @ linW + b
__global__ __launch_bounds__(256) void gather_head_kernel(
    const unsigned int* __restrict__ packed8, const unsigned int* __restrict__ ren8,
    const float4* __restrict__ xwh,   // 8 float4 (= 64 halves) per row
    const float* __restrict__ linW, const float* __restrict__ linb,
    float* __restrict__ out) {
    int gid = blockIdx.x * blockDim.x + threadIdx.x;
    int n = gid >> 6, lane = gid & 63;
    if (n >= N_NODES) return;
    int c8 = lane & 7;        // columns c8*8 .. c8*8+7
    int slot = lane >> 3;     // 8 row-slots per wave
    // per-XCD counts -> lane's (list, slot) assignment + total weighted degree
    int xsel = -1, xslot = 0, pref = 0;
    unsigned int wfix = 0;
    #pragma unroll
    for (int xx = 0; xx < NXCD; xx++) {
        unsigned int pkx = packed8[(size_t)xx * NPAD + n];   // broadcast load
        int cx = min((int)(pkx >> 24), BUCKET8);
        wfix += pkx & 0xFFFFFFu;
        if (lane >= pref && lane < pref + cx) { xsel = xx; xslot = lane - pref; }
        pref += cx;
    }
    int cnt = min(pref, 64);
    float di = rsqrtf((float)wfix * (1.0f / FIX32) + 1.0f);
    float acc[8];
    #pragma unroll
    for (int q = 0; q < 8; q++) acc[q] = 0.f;
    if (slot == 0) {
        float4 hv = xwh[n * 8 + c8];
        const __half2* h2 = reinterpret_cast<const __half2*>(&hv);
        #pragma unroll
        for (int q = 0; q < 4; q++) {
            float2 f = __half22float2(h2[q]);
            acc[2 * q]     = f.x;
            acc[2 * q + 1] = f.y;
        }
    }
    // fetch this lane's record (concatenated per-XCD lists, lane < cnt)
    int rv = 0; float wv = 0.f;
    if (xsel >= 0 && lane < cnt) {
        unsigned int rec = ren8[((size_t)xsel * N_NODES + n) * BUCKET8 + xslot];
        rv = (int)(rec & 0xFFFFu);
        __half_raw hr; hr.x = (unsigned short)(rec >> 16);
        wv = __half2float(__half(hr));
    }
    int G = (cnt + 7) >> 3;
    int g = 0;
    for (; g + 2 <= G; g += 2) {      // 16 independent gathers in flight
        int src0 = g * 8 + slot, src1 = src0 + 8;
        int   ra = __shfl(rv, src0);  float wa = __shfl(wv, src0);
        int   rb = __shfl(rv, src1);  float wb = __shfl(wv, src1);
        float4 ha = xwh[ra * 8 + c8];
        float4 hb = xwh[rb * 8 + c8];
        const __half2* h2a = reinterpret_cast<const __half2*>(&ha);
        const __half2* h2b = reinterpret_cast<const __half2*>(&hb);
        #pragma unroll
        for (int q = 0; q < 4; q++) {
            float2 fa = __half22float2(h2a[q]);
            float2 fb = __half22float2(h2b[q]);
            acc[2 * q]     += wa * fa.x + wb * fb.x;
            acc[2 * q + 1] += wa * fa.y + wb * fb.y;
        }
    }
    if (g < G) {
        int src = g * 8 + slot;
        int r = __shfl(rv, src);      // inactive slots: wv=0 -> no-op FMA
        float ww = __shfl(wv, src);
        float4 hv = xwh[r * 8 + c8];
        const __half2* h2 = reinterpret_cast<const __half2*>(&hv);
        #pragma unroll
        for (int q = 0; q < 4; q++) {
            float2 f = __half22float2(h2[q]);
            acc[2 * q]     += ww * f.x;
            acc[2 * q + 1] += ww * f.y;
        }
    }
    // reduce partial sums across the 8 slots (lane bits 3,4,5)
    #pragma unroll
    for (int q = 0; q < 8; q++) {
        acc[q] += __shfl_xor(acc[q], 8);
        acc[q] += __shfl_xor(acc[q], 16);
        acc[q] += __shfl_xor(acc[q], 32);
    }
    float pv = 0.f;
    #pragma unroll
    for (int q = 0; q < 8; q++)
        pv += fmaxf(di * acc[q], 0.f) * linW[c8 * 8 + q];
    pv += __shfl_xor(pv, 1); pv += __shfl_xor(pv, 2); pv += __shfl_xor(pv, 4);
    if (lane == 0) out[n] = pv + linb[0];
}

extern "C" void kernel_launch(void* const* d_in, const int* in_sizes, int n_in,
                              void* d_out, int out_size, void* d_ws, size_t ws_size,
                              hipStream_t stream) {
    const float* x     = (const float*)d_in[0];
    const int*   ei    = (const int*)d_in[1];
    const float* ew    = (const float*)d_in[2];
    const float* p     = (const float*)d_in[3];
    const float* initW = (const float*)d_in[4];
    const float* Wih   = (const float*)d_in[5];
    const float* Whh   = (const float*)d_in[6];
    const float* bih   = (const float*)d_in[7];
    const float* bhh   = (const float*)d_in[8];
    const float* linW  = (const float*)d_in[9];
    const float* linb  = (const float*)d_in[10];
    float* out = (float*)d_out;

    char* w = (char*)d_ws;
    unsigned int* packed8 = (unsigned int*)w; w += 4ull * NXCD * NPAD;              // 1.6 MB
    unsigned int* ren8 = (unsigned int*)w;    w += 4ull * NXCD * N_NODES * BUCKET8; // 38.4 MB
    __half* xwh    = (__half*)w;   w += 2ull * (size_t)N_NODES * DIM;               // 6.4 MB
    float* cand_val= (float*)w;    w += 4ull * 8192;
    int*   cand_idx= (int*)w;      w += 4ull * 8192;
    float* x_tilde = (float*)w;    w += 4ull * 4096;
    float* W       = (float*)w;    w += 4ull * 4096;

    // zero the 8 per-XCD counter copies (capture-legal memset node)
    hipMemsetAsync(packed8, 0, 4ull * NXCD * NPAD, stream);
    score_topk_edge_kernel<<<NB_EDGE, 512, 0, stream>>>(
        x, p, cand_val, cand_idx, ei, ew, packed8, ren8);
    topk_b_kernel<<<1, 1024, 0, stream>>>(cand_val, cand_idx, x, x_tilde);
    gru_kernel<<<16, 256, 0, stream>>>(x_tilde, initW, Wih, Whh, bih, bhh, W);
    xw_kernel<<<XW_BLOCKS, 256, 0, stream>>>(x, W, packed8, xwh);
    gather_head_kernel<<<(N_NODES * 64 + 255) / 256, 256, 0, stream>>>(
        packed8, ren8, (const float4*)xwh, linW, linb, out);
}

// Round 9
// 203.710 us; speedup vs baseline: 1.0246x; 1.0065x over previous
//
#include <hip/hip_runtime.h>
#include <hip/hip_fp16.h>
#include <cmath>

#define N_NODES 50000
#define PK_STRIDE 8          // u32 slots per counter (32B): spread atomics across lines (r22)
#define NPADW (50016 * PK_STRIDE)  // per-XCD packed8 stride in u32; node N_NODES = dummy slot
#define DIM 64
#define E_EDGES 800000
#define FIX32 65536.0f       // 2^16 fixed-point scale for deg (24-bit field, max 256)
#define NB_A 98              // score/sort blocks: 98 * 512 = 50176 >= 50000
#define NB_EDGE 391          // edge blocks: 391*512*4 = 800768 >= 800000 (4 edges/thread)
#define ESTRIDE (NB_EDGE * 512)
#define NRUNS 98             // sorted runs of 64 entering phase B
#define NXCD 8               // MI355X: 8 XCDs, per-XCD L2 (non-coherent)
#define BUCKET8 24           // per-(xcd,node) bucket capacity; deg ~Poisson(16) total
#define XW_BLOCKS 782        // ceil(50000 / 64)

// ATOMIC WALL LEDGER (r10-r24): shared+sc1=53us, per-XCD sc0=50us, 4x-batched=48.7us
// -> wall is TCC service rate, not wave latency or fabric. This kernel (r22,
// resubmitted r23/r24 after infra timeouts) tests same-line serialization:
// counters padded to 32B slots (64 -> ~8 atomics/line). Also note: edge-kernel
// gains so far have NOT moved the ~205us total; ~155us is unattributed (top-5
// saturated by edge-kernel replays) — shrinking this kernel exposes the rest.

// XCD id of the executing wave (HW-verified on gfx950: s_getreg HW_REG_XCC_ID, m09)
__device__ __forceinline__ int xcc_id() {
    int x;
    asm volatile("s_getreg_b32 %0, hwreg(HW_REG_XCC_ID)" : "=s"(x));
    return x & 7;
}

// ======== wave-register bitonic helpers (comparator: val desc, idx asc) ========
__device__ __forceinline__ void wave_sort64(float& v, int& idx, int lane) {
    #pragma unroll
    for (int k = 2; k <= 64; k <<= 1) {
        #pragma unroll
        for (int j = k >> 1; j > 0; j >>= 1) {
            float ov = __shfl_xor(v, j);
            int   oi = __shfl_xor(idx, j);
            bool lower = ((lane & j) == 0);
            bool up    = ((lane & k) == 0);
            bool mine_prec = (v > ov) || (v == ov && idx < oi);
            bool keep = up ? (lower == mine_prec) : (lower != mine_prec);
            if (!keep) { v = ov; idx = oi; }
        }
    }
}

// A (desc, in regs) merged with B (bv/bi must hold B[63-lane]); result: top-64 desc
__device__ __forceinline__ void wave_merge_top64(float& v, int& idx,
                                                 float bv, int bi, int lane) {
    bool a_prec = (v > bv) || (v == bv && idx < bi);
    if (!a_prec) { v = bv; idx = bi; }
    #pragma unroll
    for (int j = 32; j > 0; j >>= 1) {
        float ov = __shfl_xor(v, j);
        int   oi = __shfl_xor(idx, j);
        bool lower = ((lane & j) == 0);
        bool mine_prec = (v > ov) || (v == ov && idx < oi);
        bool keep = (lower == mine_prec);   // up = true (full-width merge)
        if (!keep) { v = ov; idx = oi; }
    }
}

// ------ fused: score + top-k phase A (blocks<98) + batched edge pass (all blocks) ------
__global__ __launch_bounds__(512) void score_topk_edge_kernel(
    const float* __restrict__ x, const float* __restrict__ p,
    float* __restrict__ cand_val, int* __restrict__ cand_idx,
    const int* __restrict__ ei, const float* __restrict__ ew,
    unsigned int* __restrict__ packed8, unsigned int* __restrict__ ren8) {
    __shared__ float sv[512];
    __shared__ int   si[512];
    int t = threadIdx.x, lane = t & 63, wvid = t >> 6;
    if (blockIdx.x < NB_A) {
        int g = blockIdx.x * 512 + t;
        float v; int idx;
        if (g < N_NODES) {
            const float4* x4 = (const float4*)(x + (size_t)g * DIM);
            const float4* p4 = (const float4*)p;
            float dot = 0.f, pn = 0.f;
            #pragma unroll
            for (int k = 0; k < 16; k++) {
                float4 xv = x4[k], pv = p4[k];
                dot += xv.x * pv.x + xv.y * pv.y + xv.z * pv.z + xv.w * pv.w;
                pn  += pv.x * pv.x + pv.y * pv.y + pv.z * pv.z + pv.w * pv.w;
            }
            v = dot / sqrtf(pn);
            idx = g;
        } else { v = -INFINITY; idx = 0x7fffffff; }
        wave_sort64(v, idx, lane);
        sv[t] = v; si[t] = idx;
        __syncthreads();
        if (wvid == 0) {
            #pragma unroll
            for (int r = 1; r < 8; r++)
                wave_merge_top64(v, idx, sv[r * 64 + 63 - lane], si[r * 64 + 63 - lane], lane);
            cand_val[blockIdx.x * 64 + lane] = v;
            cand_idx[blockIdx.x * 64 + lane] = idx;
        }
    }
    // ---- batched edge pass: 4 edges/thread, 4 L2-local RMWs in flight, padded slots ----
    int xcc = xcc_id();
    unsigned int* mypk  = packed8 + (size_t)xcc * NPADW;
    unsigned int* myren = ren8 + (size_t)xcc * N_NODES * BUCKET8;
    int e0 = blockIdx.x * 512 + t;       // 0 .. ESTRIDE-1
    int   rr[4]; int cc[4]; float wwv[4]; bool valid[4];
    #pragma unroll
    for (int k = 0; k < 4; k++) {
        int e = e0 + k * ESTRIDE;
        bool vld = (e < E_EDGES);
        int ie = vld ? e : 0;
        rr[k]  = ei[ie];
        cc[k]  = vld ? ei[E_EDGES + ie] : N_NODES;   // dummy slot for OOB
        wwv[k] = ew[ie];
        valid[k] = vld;
    }
    unsigned int q[4];
    unsigned int* ap[4];
    #pragma unroll
    for (int k = 0; k < 4; k++) {
        q[k] = valid[k] ? ((1u << 24) | (unsigned int)(wwv[k] * FIX32)) : 0u;
        ap[k] = &mypk[(size_t)cc[k] * PK_STRIDE];    // 32B-padded counter slot (r22)
    }
    unsigned int o0, o1, o2, o3;
    asm volatile(
        "global_atomic_add %0, %4, %8, off sc0\n\t"
        "global_atomic_add %1, %5, %9, off sc0\n\t"
        "global_atomic_add %2, %6, %10, off sc0\n\t"
        "global_atomic_add %3, %7, %11, off sc0\n\t"
        "s_waitcnt vmcnt(0)"
        : "=&v"(o0), "=&v"(o1), "=&v"(o2), "=&v"(o3)
        : "v"(ap[0]), "v"(ap[1]), "v"(ap[2]), "v"(ap[3]),
          "v"(q[0]), "v"(q[1]), "v"(q[2]), "v"(q[3])
        : "memory");
    unsigned int oo[4] = {o0, o1, o2, o3};
    #pragma unroll
    for (int k = 0; k < 4; k++) {
        unsigned int pos = oo[k] >> 24;
        if (valid[k] && pos < BUCKET8) {
            __half hw = __float2half(wwv[k]);
            unsigned int rec = ((unsigned int)__half_as_ushort(hw) << 16) | (unsigned int)rr[k];
            myren[(size_t)cc[k] * BUCKET8 + pos] = rec;
        }
    }
}

// ---------------- top-k phase B: merge 98 runs, build x_tilde (1 block) ----------------
__global__ __launch_bounds__(1024) void topk_b_kernel(
    const float* __restrict__ cand_val, const int* __restrict__ cand_idx,
    const float* __restrict__ x, float* __restrict__ x_tilde) {
    __shared__ float rsv[16 * 64];
    __shared__ int   rsi[16 * 64];
    __shared__ float tval[64];
    __shared__ int   perm[64];
    int t = threadIdx.x, lane = t & 63, wv = t >> 6;
    int r0 = wv * 8;
    float v; int idx;
    if (r0 < NRUNS) { v = cand_val[r0 * 64 + lane]; idx = cand_idx[r0 * 64 + lane]; }
    else            { v = -INFINITY; idx = 0x7fffffff; }
    for (int r = r0 + 1; r < r0 + 8 && r < NRUNS; r++)
        wave_merge_top64(v, idx, cand_val[r * 64 + 63 - lane],
                         cand_idx[r * 64 + 63 - lane], lane);
    rsv[wv * 64 + lane] = v; rsi[wv * 64 + lane] = idx;
    __syncthreads();
    if (wv == 0) {
        v = rsv[lane]; idx = rsi[lane];
        for (int r = 1; r < 16; r++)
            wave_merge_top64(v, idx, rsv[r * 64 + 63 - lane],
                             rsi[r * 64 + 63 - lane], lane);
        tval[lane] = tanhf(v);
        perm[lane] = idx;
    }
    __syncthreads();
    for (int i = t; i < 4096; i += 1024) {
        int j = i >> 6, kk = i & 63;
        x_tilde[i] = x[perm[j] * DIM + kk] * tval[j];
    }
}

// ---------------- GRU step (16 blocks x 256, 4 rows per block) ----------------
__global__ __launch_bounds__(256) void gru_kernel(
    const float* __restrict__ xt, const float* __restrict__ initW,
    const float* __restrict__ Wih, const float* __restrict__ Whh,
    const float* __restrict__ bih, const float* __restrict__ bhh,
    float* __restrict__ Wout) {
    __shared__ float xrow_s[256], hrow_s[256];
    int t = threadIdx.x;
    int i = blockIdx.x * 4 + (t >> 6);   // row 0..63
    int j = t & 63;
    int li = (t >> 6) * 64 + j;
    xrow_s[li] = xt[i * 64 + j];
    hrow_s[li] = initW[i * 64 + j];
    __syncthreads();
    int lb = (t >> 6) * 64;
    float gi_r = bih[j], gi_z = bih[j + 64], gi_n = bih[j + 128];
    float gh_r = bhh[j], gh_z = bhh[j + 64], gh_n = bhh[j + 128];
    for (int k = 0; k < 64; k++) {
        float xv = xrow_s[lb + k], hv = hrow_s[lb + k];
        gi_r += xv * Wih[j * 64 + k];
        gi_z += xv * Wih[(j + 64) * 64 + k];
        gi_n += xv * Wih[(j + 128) * 64 + k];
        gh_r += hv * Whh[j * 64 + k];
        gh_z += hv * Whh[(j + 64) * 64 + k];
        gh_n += hv * Whh[(j + 128) * 64 + k];
    }
    float r = 1.f / (1.f + expf(-(gi_r + gh_r)));
    float z = 1.f / (1.f + expf(-(gi_z + gh_z)));
    float nn = tanhf(gi_n + r * gh_n);
    Wout[i * 64 + j] = (1.f - z) * nn + z * hrow_s[lb + j];
}

// ---------------- xw = dinv[r] * (x @ W), output fp16 (pre-scaled rows) ----------------
__global__ __launch_bounds__(256) void xw_kernel(
    const float* __restrict__ x, const float* __restrict__ W,
    const unsigned int* __restrict__ packed8, __half* __restrict__ xwh) {
    __shared__ float Wl[64 * 64];
    __shared__ float Xl[64 * 64];
    __shared__ float dinv_s[64];
    int t = threadIdx.x;
    int r0 = blockIdx.x * 64;
    if (t < 64) {
        int r = r0 + t;
        unsigned int s = 0;
        if (r < N_NODES) {
            #pragma unroll
            for (int xx = 0; xx < NXCD; xx++)
                s += packed8[(size_t)xx * NPADW + (size_t)r * PK_STRIDE] & 0xFFFFFFu;
        }
        dinv_s[t] = rsqrtf((float)s * (1.0f / FIX32) + 1.0f);
    }
    for (int i = t; i < 4096; i += 256) Wl[i] = W[i];
    for (int i = t; i < 4096; i += 256) {
        int r = r0 + (i >> 6);
        Xl[i] = (r < N_NODES) ? x[r0 * 64 + i] : 0.f;
    }
    __syncthreads();
    int j = t & 63, ty = t >> 6;
    float acc[16];
    #pragma unroll
    for (int rr = 0; rr < 16; rr++) acc[rr] = 0.f;
    for (int k = 0; k < 64; k++) {
        float wvv = Wl[k * 64 + j];
        #pragma unroll
        for (int rr = 0; rr < 16; rr++)
            acc[rr] += Xl[(ty * 16 + rr) * 64 + k] * wvv;
    }
    #pragma unroll
    for (int rr = 0; rr < 16; rr++) {
        int r = r0 + ty * 16 + rr;
        if (r < N_NODES)
            xwh[r * DIM + j] = __float2half(acc[rr] * dinv_s[ty * 16 + rr]);
    }
}

// ------- gather + fused head: wave per node, walks 8 per-XCD bucket lists -------
// agg[n] = dinv[n] * (xwh[n] + sum_e w_e * xwh[row_e]);  out = relu(agg) @ linW + b
__global__ __launch_bounds__(256) void gather_head_kernel(
    const unsigned int* __restrict__ packed8, const unsigned int* __restrict__ ren8,
    const float4* __restrict__ xwh,   // 8 float4 (= 64 halves) per row
    const float* __restrict__ linW, const float* __restrict__ linb,
    float* __restrict__ out) {
    int gid = blockIdx.x * blockDim.x + threadIdx.x;
    int n = gid >> 6, lane = gid & 63;
    if (n >= N_NODES) return;
    int c8 = lane & 7;        // columns c8*8 .. c8*8+7
    int slot = lane >> 3;     // 8 row-slots per wave
    // per-XCD counts -> lane's (list, slot) assignment + total weighted degree
    int xsel = -1, xslot = 0, pref = 0;
    unsigned int wfix = 0;
    #pragma unroll
    for (int xx = 0; xx < NXCD; xx++) {
        unsigned int pkx = packed8[(size_t)xx * NPADW + (size_t)n * PK_STRIDE]; // broadcast
        int cx = min((int)(pkx >> 24), BUCKET8);
        wfix += pkx & 0xFFFFFFu;
        if (lane >= pref && lane < pref + cx) { xsel = xx; xslot = lane - pref; }
        pref += cx;
    }
    int cnt = min(pref, 64);
    float di = rsqrtf((float)wfix * (1.0f / FIX32) + 1.0f);
    float acc[8];
    #pragma unroll
    for (int q = 0; q < 8; q++) acc[q] = 0.f;
    if (slot == 0) {
        float4 hv = xwh[n * 8 + c8];
        const __half2* h2 = reinterpret_cast<const __half2*>(&hv);
        #pragma unroll
        for (int q = 0; q < 4; q++) {
            float2 f = __half22float2(h2[q]);
            acc[2 * q]     = f.x;
            acc[2 * q + 1] = f.y;
        }
    }
    // fetch this lane's record (concatenated per-XCD lists, lane < cnt)
    int rv = 0; float wv = 0.f;
    if (xsel >= 0 && lane < cnt) {
        unsigned int rec = ren8[((size_t)xsel * N_NODES + n) * BUCKET8 + xslot];
        rv = (int)(rec & 0xFFFFu);
        __half_raw hr; hr.x = (unsigned short)(rec >> 16);
        wv = __half2float(__half(hr));
    }
    int G = (cnt + 7) >> 3;
    int g = 0;
    for (; g + 2 <= G; g += 2) {      // 16 independent gathers in flight
        int src0 = g * 8 + slot, src1 = src0 + 8;
        int   ra = __shfl(rv, src0);  float wa = __shfl(wv, src0);
        int   rb = __shfl(rv, src1);  float wb = __shfl(wv, src1);
        float4 ha = xwh[ra * 8 + c8];
        float4 hb = xwh[rb * 8 + c8];
        const __half2* h2a = reinterpret_cast<const __half2*>(&ha);
        const __half2* h2b = reinterpret_cast<const __half2*>(&hb);
        #pragma unroll
        for (int q = 0; q < 4; q++) {
            float2 fa = __half22float2(h2a[q]);
            float2 fb = __half22float2(h2b[q]);
            acc[2 * q]     += wa * fa.x + wb * fb.x;
            acc[2 * q + 1] += wa * fa.y + wb * fb.y;
        }
    }
    if (g < G) {
        int src = g * 8 + slot;
        int r = __shfl(rv, src);      // inactive slots: wv=0 -> no-op FMA
        float ww = __shfl(wv, src);
        float4 hv = xwh[r * 8 + c8];
        const __half2* h2 = reinterpret_cast<const __half2*>(&hv);
        #pragma unroll
        for (int q = 0; q < 4; q++) {
            float2 f = __half22float2(h2[q]);
            acc[2 * q]     += ww * f.x;
            acc[2 * q + 1] += ww * f.y;
        }
    }
    // reduce partial sums across the 8 slots (lane bits 3,4,5)
    #pragma unroll
    for (int q = 0; q < 8; q++) {
        acc[q] += __shfl_xor(acc[q], 8);
        acc[q] += __shfl_xor(acc[q], 16);
        acc[q] += __shfl_xor(acc[q], 32);
    }
    float pv = 0.f;
    #pragma unroll
    for (int q = 0; q < 8; q++)
        pv += fmaxf(di * acc[q], 0.f) * linW[c8 * 8 + q];
    pv += __shfl_xor(pv, 1); pv += __shfl_xor(pv, 2); pv += __shfl_xor(pv, 4);
    if (lane == 0) out[n] = pv + linb[0];
}

extern "C" void kernel_launch(void* const* d_in, const int* in_sizes, int n_in,
                              void* d_out, int out_size, void* d_ws, size_t ws_size,
                              hipStream_t stream) {
    const float* x     = (const float*)d_in[0];
    const int*   ei    = (const int*)d_in[1];
    const float* ew    = (const float*)d_in[2];
    const float* p     = (const float*)d_in[3];
    const float* initW = (const float*)d_in[4];
    const float* Wih   = (const float*)d_in[5];
    const float* Whh   = (const float*)d_in[6];
    const float* bih   = (const float*)d_in[7];
    const float* bhh   = (const float*)d_in[8];
    const float* linW  = (const float*)d_in[9];
    const float* linb  = (const float*)d_in[10];
    float* out = (float*)d_out;

    char* w = (char*)d_ws;
    unsigned int* packed8 = (unsigned int*)w; w += 4ull * NXCD * NPADW;             // 12.8 MB
    unsigned int* ren8 = (unsigned int*)w;    w += 4ull * NXCD * N_NODES * BUCKET8; // 38.4 MB
    __half* xwh    = (__half*)w;   w += 2ull * (size_t)N_NODES * DIM;               // 6.4 MB
    float* cand_val= (float*)w;    w += 4ull * 8192;
    int*   cand_idx= (int*)w;      w += 4ull * 8192;
    float* x_tilde = (float*)w;    w += 4ull * 4096;
    float* W       = (float*)w;    w += 4ull * 4096;

    // zero the 8 per-XCD padded counter copies (capture-legal memset node)
    hipMemsetAsync(packed8, 0, 4ull * NXCD * NPADW, stream);
    score_topk_edge_kernel<<<NB_EDGE, 512, 0, stream>>>(
        x, p, cand_val, cand_idx, ei, ew, packed8, ren8);
    topk_b_kernel<<<1, 1024, 0, stream>>>(cand_val, cand_idx, x, x_tilde);
    gru_kernel<<<16, 256, 0, stream>>>(x_tilde, initW, Wih, Whh, bih, bhh, W);
    xw_kernel<<<XW_BLOCKS, 256, 0, stream>>>(x, W, packed8, xwh);
    gather_head_kernel<<<(N_NODES * 64 + 255) / 256, 256, 0, stream>>>(
        packed8, ren8, (const float4*)xwh, linW, linb, out);
}